// Round 10
// baseline (526.645 us; speedup 1.0000x reference)
//
#include <hip/hip_runtime.h>
#include <hip/hip_bf16.h>
#include <math.h>

#define B_   32
#define T_   4096
#define D_   1024
#define H_   256
#define KTH  2048           // threshold_index = int(T*0.5)
#define SC   64             // pv chunks per batch
#define BK   32
#define NT   (D_/BK)        // 32 k-steps
#define BSZ  (H_*BK)        // 8192 ushorts per B buf (16 KB)
#define EPSB 4.0e-3f        // refinement band half-width (~8 sigma of bf16 e-error)
#define MAXBAND 256
#define RB   4              // refine rows per block-group

typedef __attribute__((ext_vector_type(8))) short short8;
typedef __attribute__((ext_vector_type(4))) float f32x4;

#define VM8()  asm volatile("s_waitcnt vmcnt(8)" ::: "memory")
#define GLL(src, dst) __builtin_amdgcn_global_load_lds( \
    (const __attribute__((address_space(1))) unsigned int*)(src), \
    (__attribute__((address_space(3))) unsigned int*)(dst), 16, 0, 0)

// ---------- helpers ----------
__device__ inline unsigned f2s(float f) {
    unsigned u = __float_as_uint(f);
    return (u & 0x80000000u) ? ~u : (u | 0x80000000u);
}
__device__ inline float s2f(unsigned s) {
    unsigned x = (s & 0x80000000u) ? (s & 0x7fffffffu) : ~s;
    return __uint_as_float(x);
}
__device__ inline unsigned f2bf_rne(float f) {      // round-to-nearest-even bf16
    unsigned u = __float_as_uint(f);
    return (u + 0x7FFFu + ((u >> 16) & 1u)) >> 16;
}
__device__ inline unsigned pk2(float a, float b) {
    return f2bf_rne(a) | (f2bf_rne(b) << 16);
}
__device__ inline int block_sum_i(int v, int* sb, int tid) {
    #pragma unroll
    for (int o = 32; o; o >>= 1) v += __shfl_down(v, o);
    __syncthreads();
    if ((tid & 63) == 0) sb[tid >> 6] = v;
    __syncthreads();
    return sb[0] + sb[1] + sb[2] + sb[3];
}
__device__ inline float block_max_f(float v, float* sb, int tid) {
    #pragma unroll
    for (int o = 32; o; o >>= 1) v = fmaxf(v, __shfl_down(v, o));
    __syncthreads();
    if ((tid & 63) == 0) sb[tid >> 6] = v;
    __syncthreads();
    return fmaxf(fmaxf(sb[0], sb[1]), fmaxf(sb[2], sb[3]));
}
__device__ inline float block_sum_f(float v, float* sb, int tid) {
    #pragma unroll
    for (int o = 32; o; o >>= 1) v += __shfl_down(v, o);
    __syncthreads();
    if ((tid & 63) == 0) sb[tid >> 6] = v;
    __syncthreads();
    return sb[0] + sb[1] + sb[2] + sb[3];
}

// ---------- W1 [K][N] fp32 -> W1T bf16(RNE) [N][K] ----------
__global__ __launch_bounds__(256) void k_w1t(const float* __restrict__ W1,
                                             ushort* __restrict__ Whi) {
    __shared__ float tile[32][33];
    const int kb = blockIdx.x * 32, nb = blockIdx.y * 32;
    const int tx = threadIdx.x & 31, ty = threadIdx.x >> 5;   // ty 0..7
    #pragma unroll
    for (int i = 0; i < 4; i++)
        tile[ty + 8*i][tx] = W1[(long)(kb + ty + 8*i) * H_ + nb + tx];
    __syncthreads();
    #pragma unroll
    for (int i = 0; i < 4; i++) {
        long o = (long)(nb + ty + 8*i) * D_ + kb + tx;
        Whi[o] = (ushort)f2bf_rne(tile[tx][ty + 8*i]);
    }
}

// ---------- phase 1: barrier-free wave-independent MFMA GEMM -> e ----------
// Block = 64 rows x 256 cols, 256 thr = 4 waves, wave = 64x64 (wn = col panel).
// NO cross-wave LDS sharing: each wave gload_lds-stages ITS OWN B panel
// (double-buffered, 4 chunks/step) and keeps A in registers (loaded per-frag,
// packed to bf16, reissued for t+1 in the same regs). Sync = one per-wave
// counted vmcnt(8) per step. No barriers until the epilogue.
// LDS B layout [slab=n>>4][kc][n&15][8] -> frag ds_read_b128 = base+lane*16.
__global__ __launch_bounds__(256, 3) void k_e_mfma(
    const float* __restrict__ x,
    const ushort* __restrict__ Whi,
    const float* __restrict__ b1, const float* __restrict__ W2,
    const float* __restrict__ b2, float* __restrict__ e_out)
{
    __shared__ ushort sB[2 * BSZ];   // 32 KB
    __shared__ float  sRed[4][64];   // 1 KB

    const int tid  = threadIdx.x;
    const int lane = tid & 63;
    const int wn   = tid >> 6;              // col panel 0..3
    const int l15  = lane & 15, lg = lane >> 4;
    const long row0 = (long)blockIdx.x * 64;

    // A fragment pointers: frag fm -> x[row0 + fm*16 + l15, lg*8 ...]
    const float* aptr[4];
    #pragma unroll
    for (int fm = 0; fm < 4; fm++)
        aptr[fm] = x + (row0 + fm * 16 + l15) * (long)D_ + lg * 8;

    // B staging (own panel): instr j stages chunks L = (wn*4+j)*64 + lane
    //   chunk L holds (n = (L>>6)*16 + (L&15), kc = (L>>4)&3)
    const ushort* bsrc[4];
    int bdst[4];
    #pragma unroll
    for (int j = 0; j < 4; j++) {
        const int L0 = (wn * 4 + j) * 64;
        const int L  = L0 + lane;
        const int n  = (L >> 6) * 16 + (L & 15);
        const int kc = (L >> 4) & 3;
        bsrc[j] = Whi + (long)n * D_ + kc * 8;
        bdst[j] = L0 * 8;                       // uniform base (ushort idx)
    }

    // B fragment read offsets: frag fn at n=wn*64+fn*16+l15, kc=lg
    int boff[4];
    #pragma unroll
    for (int fn = 0; fn < 4; fn++)
        boff[fn] = (wn * 4 + fn) * 512 + lg * 128 + l15 * 8;

    f32x4 acc[4][4];
    #pragma unroll
    for (int i = 0; i < 4; i++)
        #pragma unroll
        for (int j = 0; j < 4; j++) acc[i][j] = (f32x4){0.f, 0.f, 0.f, 0.f};

    float4 ArA[4], ArB[4];

    // prologue: B(0) -> buf0, A(0) -> regs
    #pragma unroll
    for (int j = 0; j < 4; j++) GLL(bsrc[j], &sB[bdst[j]]);
    #pragma unroll
    for (int fm = 0; fm < 4; fm++) {
        ArA[fm] = *(const float4*)(aptr[fm]);
        ArB[fm] = *(const float4*)(aptr[fm] + 4);
    }

    for (int t = 0; t < NT; ++t) {
        const ushort* sbp = sB + (t & 1) * BSZ;
        ushort* sbn = sB + ((t & 1) ^ 1) * BSZ;
        VM8();                                   // own B(t) landed (oldest 4)
        short8 bfr[4];
        #pragma unroll
        for (int fn = 0; fn < 4; fn++)
            bfr[fn] = *(const short8*)&sbp[boff[fn]];
        if (t + 1 < NT) {
            const int ko = (t + 1) * BK;
            #pragma unroll
            for (int j = 0; j < 4; j++) GLL(bsrc[j] + ko, &sbn[bdst[j]]);
            #pragma unroll
            for (int fm = 0; fm < 4; fm++) {
                // pack A(t), then reissue A(t+1) into the same regs (WAR-safe)
                union { uint4 u4; short8 s8; } cv;
                cv.u4 = make_uint4(pk2(ArA[fm].x, ArA[fm].y), pk2(ArA[fm].z, ArA[fm].w),
                                   pk2(ArB[fm].x, ArB[fm].y), pk2(ArB[fm].z, ArB[fm].w));
                ArA[fm] = *(const float4*)(aptr[fm] + ko);
                ArB[fm] = *(const float4*)(aptr[fm] + ko + 4);
                __builtin_amdgcn_s_setprio(1);
                #pragma unroll
                for (int fn = 0; fn < 4; fn++)
                    acc[fm][fn] = __builtin_amdgcn_mfma_f32_16x16x32_bf16(cv.s8, bfr[fn], acc[fm][fn], 0, 0, 0);
                __builtin_amdgcn_s_setprio(0);
            }
        } else {
            #pragma unroll
            for (int fm = 0; fm < 4; fm++) {
                union { uint4 u4; short8 s8; } cv;
                cv.u4 = make_uint4(pk2(ArA[fm].x, ArA[fm].y), pk2(ArA[fm].z, ArA[fm].w),
                                   pk2(ArB[fm].x, ArB[fm].y), pk2(ArB[fm].z, ArB[fm].w));
                __builtin_amdgcn_s_setprio(1);
                #pragma unroll
                for (int fn = 0; fn < 4; fn++)
                    acc[fm][fn] = __builtin_amdgcn_mfma_f32_16x16x32_bf16(cv.s8, bfr[fn], acc[fm][fn], 0, 0, 0);
                __builtin_amdgcn_s_setprio(0);
            }
        }
    }

    // epilogue: e partial = sum_j tanh(G+b1[j])*W2[j]; D frag: col=l15, row=lg*4+r
    float b1v[4], w2v[4];
    #pragma unroll
    for (int fn = 0; fn < 4; fn++) {
        int j = wn * 64 + fn * 16 + l15;
        b1v[fn] = b1[j]; w2v[fn] = W2[j];
    }
    #pragma unroll
    for (int fm = 0; fm < 4; fm++) {
        #pragma unroll
        for (int r = 0; r < 4; r++) {
            float s = 0.f;
            #pragma unroll
            for (int fn = 0; fn < 4; fn++)
                s += tanhf(acc[fm][fn][r] + b1v[fn]) * w2v[fn];
            s += __shfl_xor(s, 1); s += __shfl_xor(s, 2);
            s += __shfl_xor(s, 4); s += __shfl_xor(s, 8);
            if (l15 == 0) sRed[wn][fm * 16 + lg * 4 + r] = s;
        }
    }
    __syncthreads();
    if (tid < 64)
        e_out[row0 + tid] = sRed[0][tid] + sRed[1][tid] + sRed[2][tid] + sRed[3][tid] + b2[0];
}

// ---------- phase 2: rank threshold; BUILD=1 -> band list, BUILD=0 -> survivor list ----------
// thread handles 16 CONSECUTIVE t (t = tid*16+i) so compaction is t-ordered.
template<int BUILD>
__global__ __launch_bounds__(256) void k_thresh(const float* __restrict__ e,
                                                int* __restrict__ counts,
                                                int* __restrict__ list,
                                                int* __restrict__ sidx,
                                                float* __restrict__ sval,
                                                int* __restrict__ scount) {
    __shared__ int   sbi[4];
    __shared__ float sbf[4];
    __shared__ int   wsum[4];
    __shared__ int   scnt;
    const int b = blockIdx.x, tid = threadIdx.x;
    const int lane = tid & 63, wid = tid >> 6;
    const float* eb = e + (long)b * T_;
    const int t0 = tid * 16;

    float fe[16]; unsigned ue[16];
    #pragma unroll
    for (int i = 0; i < 16; i += 4) {
        float4 v = *(const float4*)(eb + t0 + i);
        fe[i] = v.x; fe[i+1] = v.y; fe[i+2] = v.z; fe[i+3] = v.w;
    }
    #pragma unroll
    for (int i = 0; i < 16; i++) ue[i] = f2s(fe[i]);

    unsigned lo = 0u, hi = 0xFFFFFFFFu;
    while (lo < hi) {
        unsigned mid = lo + ((hi - lo) >> 1);
        int c = 0;
        #pragma unroll
        for (int i = 0; i < 16; i++) c += (ue[i] <= mid) ? 1 : 0;
        int total = block_sum_i(c, sbi, tid);
        if (total >= KTH + 1) hi = mid; else lo = mid + 1;
    }
    const float thr = s2f(lo);

    if (BUILD) {
        if (tid == 0) scnt = 0;
        __syncthreads();
        #pragma unroll
        for (int i = 0; i < 16; i++) {
            if (fabsf(fe[i] - thr) <= EPSB) {
                int p = atomicAdd(&scnt, 1);
                if (p < MAXBAND) list[b * MAXBAND + p] = t0 + i;
            }
        }
        __syncthreads();
        if (tid == 0) counts[b] = scnt < MAXBAND ? scnt : MAXBAND;
    } else {
        float m = -INFINITY;
        #pragma unroll
        for (int i = 0; i < 16; i++) if (fe[i] < thr) m = fmaxf(m, fe[i]);
        m = block_max_f(m, sbf, tid);
        float s = 0.f;
        #pragma unroll
        for (int i = 0; i < 16; i++) if (fe[i] < thr) s += expf(fe[i] - m);
        s = block_sum_f(s, sbf, tid);
        const float inv = 1.0f / s;

        // deterministic t-ordered compaction: block exclusive scan of counts
        int c = 0;
        #pragma unroll
        for (int i = 0; i < 16; i++) c += (fe[i] < thr) ? 1 : 0;
        int p = c;
        #pragma unroll
        for (int o = 1; o < 64; o <<= 1) {
            int y = __shfl_up(p, o);
            if (lane >= o) p += y;
        }
        if (lane == 63) wsum[wid] = p;          // wave total
        __syncthreads();
        int base = 0;
        #pragma unroll
        for (int w = 0; w < 4; w++) base += (w < wid) ? wsum[w] : 0;
        int pos = base + p - c;                 // exclusive prefix
        #pragma unroll
        for (int i = 0; i < 16; i++) {
            if (fe[i] < thr) {
                sidx[(long)b * T_ + pos] = t0 + i;
                sval[(long)b * T_ + pos] = expf(fe[i] - m) * inv;
                pos++;
            }
        }
        if (tid == 0) scount[b] = wsum[0] + wsum[1] + wsum[2] + wsum[3];
    }
}

// ---------- phase 2.5: exact fp32 recompute of band rows, RB rows share one W1 stream ----------
__global__ __launch_bounds__(256) void k_refine(const float* __restrict__ x,
        const float* __restrict__ W1, const float* __restrict__ b1,
        const float* __restrict__ W2, const float* __restrict__ b2,
        const int* __restrict__ counts, const int* __restrict__ list,
        float* __restrict__ e) {
    const int b   = blockIdx.y;
    const int blk = blockIdx.x;            // 0..15
    const int cnt = counts[b];
    const int tid = threadIdx.x;
    __shared__ float xs[RB][D_];           // 16 KB
    __shared__ float sbf[4];

    for (int g = blk * RB; g < cnt; g += 16 * RB) {
        const int nr = min(RB, cnt - g);
        for (int j = 0; j < nr; j++) {
            const int t = list[b * MAXBAND + g + j];
            *(float4*)&xs[j][tid * 4] =
                *(const float4*)&x[((long)b * T_ + t) * D_ + tid * 4];
        }
        __syncthreads();

        float a0 = 0.f, a1 = 0.f, a2 = 0.f, a3 = 0.f;
        for (int k0 = 0; k0 < D_; k0 += 4) {
            const float w0 = W1[(long)(k0 + 0) * H_ + tid];
            const float w1v = W1[(long)(k0 + 1) * H_ + tid];
            const float w2q = W1[(long)(k0 + 2) * H_ + tid];
            const float w3 = W1[(long)(k0 + 3) * H_ + tid];
            {
                float4 xv = *(const float4*)&xs[0][k0];
                a0 = fmaf(xv.x, w0, a0); a0 = fmaf(xv.y, w1v, a0);
                a0 = fmaf(xv.z, w2q, a0); a0 = fmaf(xv.w, w3, a0);
            }
            {
                float4 xv = *(const float4*)&xs[1][k0];
                a1 = fmaf(xv.x, w0, a1); a1 = fmaf(xv.y, w1v, a1);
                a1 = fmaf(xv.z, w2q, a1); a1 = fmaf(xv.w, w3, a1);
            }
            {
                float4 xv = *(const float4*)&xs[2][k0];
                a2 = fmaf(xv.x, w0, a2); a2 = fmaf(xv.y, w1v, a2);
                a2 = fmaf(xv.z, w2q, a2); a2 = fmaf(xv.w, w3, a2);
            }
            {
                float4 xv = *(const float4*)&xs[3][k0];
                a3 = fmaf(xv.x, w0, a3); a3 = fmaf(xv.y, w1v, a3);
                a3 = fmaf(xv.z, w2q, a3); a3 = fmaf(xv.w, w3, a3);
            }
        }

        float aj[RB] = {a0, a1, a2, a3};
        for (int j = 0; j < nr; j++) {
            float v = tanhf(aj[j] + b1[tid]) * W2[tid];
            float tot = block_sum_f(v, sbf, tid);
            if (tid == 0) {
                const int t = list[b * MAXBAND + g + j];
                e[(long)b * T_ + t] = tot + b2[0];
            }
            __syncthreads();
        }
        __syncthreads();
    }
}

// ---------- phase 3: dense survivor-list PV ----------
__global__ __launch_bounds__(256) void k_pv(const float* __restrict__ x,
                                            const int* __restrict__ sidx,
                                            const float* __restrict__ sval,
                                            const int* __restrict__ scount,
                                            float* __restrict__ partial) {
    const int c = blockIdx.x, b = blockIdx.y, tid = threadIdx.x;
    const int cnt = scount[b];
    const int len = (cnt + SC - 1) / SC;       // <= 32 (cnt <= 2048)
    const int k0 = c * len;
    const int nl = min(len, cnt - k0);
    __shared__ int   si[32];
    __shared__ float sv[32];
    if (tid < nl) {
        si[tid] = sidx[(long)b * T_ + k0 + tid];
        sv[tid] = sval[(long)b * T_ + k0 + tid];
    }
    __syncthreads();

    float4 acc = {0.f, 0.f, 0.f, 0.f};
    const float* xb = x + (long)b * T_ * D_ + tid * 4;
    #pragma unroll 4
    for (int k = 0; k < nl; k++) {
        const float w = sv[k];
        float4 v = *(const float4*)(xb + (long)si[k] * D_);
        acc.x = fmaf(w, v.x, acc.x);
        acc.y = fmaf(w, v.y, acc.y);
        acc.z = fmaf(w, v.z, acc.z);
        acc.w = fmaf(w, v.w, acc.w);
    }
    *(float4*)&partial[(((long)b * SC) + c) * D_ + tid * 4] = acc;
}

// ---------- phase 4 ----------
__global__ __launch_bounds__(256) void k_red(const float* __restrict__ partial,
                                             float* __restrict__ out) {
    const int b = blockIdx.x, tid = threadIdx.x;
    float4 acc = {0.f, 0.f, 0.f, 0.f};
    #pragma unroll
    for (int c = 0; c < SC; c++) {
        float4 v = *(const float4*)&partial[(((long)b * SC) + c) * D_ + tid * 4];
        acc.x += v.x; acc.y += v.y; acc.z += v.z; acc.w += v.w;
    }
    *(float4*)&out[(long)b * D_ + tid * 4] = acc;
}

extern "C" void kernel_launch(void* const* d_in, const int* in_sizes, int n_in,
                              void* d_out, int out_size, void* d_ws, size_t ws_size,
                              hipStream_t stream) {
    const float* x  = (const float*)d_in[0];
    const float* W1 = (const float*)d_in[1];
    const float* b1 = (const float*)d_in[2];
    const float* W2 = (const float*)d_in[3];
    const float* b2 = (const float*)d_in[4];
    float* out = (float*)d_out;

    char* ws = (char*)d_ws;
    float* e       = (float*)ws;  ws += (size_t)B_ * T_ * 4;
    int*   sidx    = (int*)ws;    ws += (size_t)B_ * T_ * 4;
    float* sval    = (float*)ws;  ws += (size_t)B_ * T_ * 4;
    float* partial = (float*)ws;  ws += (size_t)B_ * SC * D_ * 4;
    ushort* Whi    = (ushort*)ws; ws += (size_t)H_ * D_ * 2;
    int* counts    = (int*)ws;    ws += 128;
    int* scountp   = (int*)ws;    ws += 128;
    int* list      = (int*)ws;

    k_w1t<<<dim3(D_ / 32, H_ / 32), 256, 0, stream>>>(W1, Whi);
    k_e_mfma<<<(B_ * T_) / 64, 256, 0, stream>>>(x, Whi, b1, W2, b2, e);
    k_thresh<1><<<B_, 256, 0, stream>>>(e, counts, list, sidx, sval, scountp);
    k_refine<<<dim3(16, B_), 256, 0, stream>>>(x, W1, b1, W2, b2, counts, list, e);
    k_thresh<0><<<B_, 256, 0, stream>>>(e, counts, list, sidx, sval, scountp);
    k_pv<<<dim3(SC, B_), 256, 0, stream>>>(x, sidx, sval, scountp, partial);
    k_red<<<B_, 256, 0, stream>>>(partial, out);
}

// Round 11
// 413.937 us; speedup vs baseline: 1.2723x; 1.2723x over previous
//
#include <hip/hip_runtime.h>
#include <hip/hip_bf16.h>
#include <math.h>

#define B_   32
#define T_   4096
#define D_   1024
#define H_   256
#define KTH  2048           // threshold_index = int(T*0.5)
#define SC   64             // pv chunks per batch
#define BK   32
#define NT   (D_/BK)        // 32 k-steps
#define EPSB 4.0e-3f        // refinement band half-width (~8 sigma of bf16 e-error)
#define MAXBAND 256
#define RB   4              // refine rows per block-group

typedef __attribute__((ext_vector_type(8))) short short8;
typedef __attribute__((ext_vector_type(4))) float f32x4;

#define FENCE6() asm volatile("s_waitcnt vmcnt(6) lgkmcnt(0)" ::: "memory")
#define FENCE0() asm volatile("s_waitcnt vmcnt(0) lgkmcnt(0)" ::: "memory")
#define BARRIER() __builtin_amdgcn_s_barrier()
#define GLL(src, dst) __builtin_amdgcn_global_load_lds( \
    (const __attribute__((address_space(1))) unsigned int*)(src), \
    (__attribute__((address_space(3))) unsigned int*)(dst), 16, 0, 0)

// ---------- helpers ----------
__device__ inline unsigned f2s(float f) {
    unsigned u = __float_as_uint(f);
    return (u & 0x80000000u) ? ~u : (u | 0x80000000u);
}
__device__ inline float s2f(unsigned s) {
    unsigned x = (s & 0x80000000u) ? (s & 0x7fffffffu) : ~s;
    return __uint_as_float(x);
}
__device__ inline unsigned f2bf_rne(float f) {      // round-to-nearest-even bf16
    unsigned u = __float_as_uint(f);
    return (u + 0x7FFFu + ((u >> 16) & 1u)) >> 16;
}
__device__ inline unsigned pk2(float a, float b) {
    return f2bf_rne(a) | (f2bf_rne(b) << 16);
}
__device__ inline int block_sum_i(int v, int* sb, int tid) {
    #pragma unroll
    for (int o = 32; o; o >>= 1) v += __shfl_down(v, o);
    __syncthreads();
    if ((tid & 63) == 0) sb[tid >> 6] = v;
    __syncthreads();
    return sb[0] + sb[1] + sb[2] + sb[3];
}
__device__ inline float block_max_f(float v, float* sb, int tid) {
    #pragma unroll
    for (int o = 32; o; o >>= 1) v = fmaxf(v, __shfl_down(v, o));
    __syncthreads();
    if ((tid & 63) == 0) sb[tid >> 6] = v;
    __syncthreads();
    return fmaxf(fmaxf(sb[0], sb[1]), fmaxf(sb[2], sb[3]));
}
__device__ inline float block_sum_f(float v, float* sb, int tid) {
    #pragma unroll
    for (int o = 32; o; o >>= 1) v += __shfl_down(v, o);
    __syncthreads();
    if ((tid & 63) == 0) sb[tid >> 6] = v;
    __syncthreads();
    return sb[0] + sb[1] + sb[2] + sb[3];
}

// ---------- W1 [K][N] fp32 -> W1T bf16(RNE) [N][K] ----------
__global__ __launch_bounds__(256) void k_w1t(const float* __restrict__ W1,
                                             ushort* __restrict__ Whi) {
    __shared__ float tile[32][33];
    const int kb = blockIdx.x * 32, nb = blockIdx.y * 32;
    const int tx = threadIdx.x & 31, ty = threadIdx.x >> 5;   // ty 0..7
    #pragma unroll
    for (int i = 0; i < 4; i++)
        tile[ty + 8*i][tx] = W1[(long)(kb + ty + 8*i) * H_ + nb + tx];
    __syncthreads();
    #pragma unroll
    for (int i = 0; i < 4; i++) {
        long o = (long)(nb + ty + 8*i) * D_ + kb + tx;
        Whi[o] = (ushort)f2bf_rne(tile[tx][ty + 8*i]);
    }
}

// ---------- phase 1: R6 schedule at 128x128 / 4 blocks-per-CU -> e partials ----------
// Block = 128 rows x 128 cols, 256 thr = 4 waves (2m x 2n). grid (2 n-tiles, 1024 m).
// A: reg-staged 2 tiles deep (4 float4/thr), cvt+ds_write late, 2 bufs.
// B: global_load_lds 16B, 3 rotating bufs, staged 2 tiles ahead.
// Fence: vmcnt(6)+lgkmcnt(0) per step (6 = the 6 newest ops: 4 A-reg + 2 B-GLL of
// step t; drains step t-1's -> B(t),A(t) ready). vmcnt(0) only at peeled last step.
// LDS 40KB exactly (sRed aliased onto sA) -> 4 blocks/CU = 4 independent barrier
// domains per CU covering each other's fence stalls.
// LDS fragment-major: [slab=row>>4][kc=k>>3][row&15][8] -> frag ds_read_b128 =
// base+lane*16, conflict-free.
__global__ __launch_bounds__(256, 4) void k_e_mfma(
    const float* __restrict__ x,
    const ushort* __restrict__ Whi,
    const float* __restrict__ b1, const float* __restrict__ W2,
    float* __restrict__ epart)
{
    __shared__ ushort sA[2 * 4096];   // 16 KB (2 bufs)
    __shared__ ushort sB[3 * 4096];   // 24 KB (3 bufs)

    const int tid  = threadIdx.x;
    const int lane = tid & 63;
    const int wv   = tid >> 6;
    const int wm   = wv >> 1, wn = wv & 1;
    const int l15  = lane & 15, lg = lane >> 4;
    const int nt   = blockIdx.x;                 // n-tile 0/1
    const int nc0  = nt * 128;
    const long row0 = (long)blockIdx.y * 128;

    // A staging: thread -> row ar=tid>>1, k-sixteenth aq=tid&1 (16 fp32 = 64B)
    const int ar = tid >> 1, aq = tid & 1;
    const float* aga = x + (row0 + ar) * (long)D_ + aq * 16;
    const int awo0 = (ar >> 4) * 512 + (aq * 2) * 128 + (ar & 15) * 8;
    const int awo1 = awo0 + 128;

    // B staging: 2 chunks/thread; chunk c = wv*128 + j*64 + lane
    //   c -> n_local=(c>>6)*16+(c&15), kc=(c>>4)&3; dst base uniform = (wv*128+j*64)*8
    const ushort* bsrc0;
    const ushort* bsrc1;
    {
        const int c0 = wv * 128 + lane;
        const int c1 = wv * 128 + 64 + lane;
        bsrc0 = Whi + (long)(nc0 + (c0 >> 6) * 16 + (c0 & 15)) * D_ + ((c0 >> 4) & 3) * 8;
        bsrc1 = Whi + (long)(nc0 + (c1 >> 6) * 16 + (c1 & 15)) * D_ + ((c1 >> 4) & 3) * 8;
    }
    const int bb0 = (wv * 128) * 8;
    const int bb1 = (wv * 128 + 64) * 8;

    // fragment read offsets
    int aoff[4], boff[4];
    #pragma unroll
    for (int f = 0; f < 4; f++) {
        aoff[f] = (wm * 4 + f) * 512 + lg * 128 + l15 * 8;
        boff[f] = (wn * 4 + f) * 512 + lg * 128 + l15 * 8;
    }

    f32x4 acc[4][4];
    #pragma unroll
    for (int i = 0; i < 4; i++)
        #pragma unroll
        for (int j = 0; j < 4; j++) acc[i][j] = (f32x4){0.f, 0.f, 0.f, 0.f};

    float4 Ra[4], Rb[4];

#define LOADA(R, T) do { \
    _Pragma("unroll") \
    for (int q = 0; q < 4; q++) (R)[q] = *(const float4*)(aga + (T) * BK + q * 4); \
} while (0)

#define WRITEA(BUF, R) do { \
    uint4 _u0 = make_uint4(pk2((R)[0].x,(R)[0].y), pk2((R)[0].z,(R)[0].w), \
                           pk2((R)[1].x,(R)[1].y), pk2((R)[1].z,(R)[1].w)); \
    uint4 _u1 = make_uint4(pk2((R)[2].x,(R)[2].y), pk2((R)[2].z,(R)[2].w), \
                           pk2((R)[3].x,(R)[3].y), pk2((R)[3].z,(R)[3].w)); \
    *(uint4*)&sA[(BUF) * 4096 + awo0] = _u0; \
    *(uint4*)&sA[(BUF) * 4096 + awo1] = _u1; \
} while (0)

#define STAGEB(T, BUF) do { \
    GLL(bsrc0 + (T) * BK, &sB[(BUF) * 4096 + bb0]); \
    GLL(bsrc1 + (T) * BK, &sB[(BUF) * 4096 + bb1]); \
} while (0)

#define COMPUTE(ABUF, BBUF) do { \
    const ushort* _sa = sA + (ABUF) * 4096; \
    const ushort* _sb = sB + (BBUF) * 4096; \
    short8 _bfr[4]; \
    _Pragma("unroll") \
    for (int fn = 0; fn < 4; fn++) _bfr[fn] = *(const short8*)&_sb[boff[fn]]; \
    __builtin_amdgcn_s_setprio(1); \
    _Pragma("unroll") \
    for (int fm = 0; fm < 4; fm++) { \
        short8 _afr = *(const short8*)&_sa[aoff[fm]]; \
        _Pragma("unroll") \
        for (int fn = 0; fn < 4; fn++) \
            acc[fm][fn] = __builtin_amdgcn_mfma_f32_16x16x32_bf16(_afr, _bfr[fn], acc[fm][fn], 0, 0, 0); \
    } \
    __builtin_amdgcn_s_setprio(0); \
} while (0)

    // prologue: A(0)->Ra, write A(0)->sA0; A(1)->Rb (held); B(0)->buf0, B(1)->buf1
    LOADA(Ra, 0);
    STAGEB(0, 0);
    LOADA(Rb, 1);
    STAGEB(1, 1);
    WRITEA(0, Ra);

    for (int t = 0; t < NT - 2; t += 2) {
        // even step t: compute sA[0],sB[t%3]; load A(t+2)->Ra; stage B(t+2); write A(t+1) from Rb
        FENCE6(); BARRIER();
        LOADA(Ra, t + 2);
        STAGEB(t + 2, (t + 2) % 3);
        COMPUTE(0, t % 3);
        WRITEA(1, Rb);
        // odd step t+1: compute sA[1],sB[(t+1)%3]; load A(t+3)->Rb; stage B(t+3); write A(t+2) from Ra
        FENCE6(); BARRIER();
        LOADA(Rb, t + 3);
        STAGEB(t + 3, (t + 3) % 3);
        COMPUTE(1, (t + 1) % 3);
        WRITEA(0, Ra);
    }
    // t = 30 (even): nothing left to stage; write A(31) from Rb
    FENCE6(); BARRIER();
    COMPUTE(0, (NT - 2) % 3);
    WRITEA(1, Rb);
    // t = 31: final drain
    FENCE0(); BARRIER();
    COMPUTE(1, (NT - 1) % 3);

#undef COMPUTE
#undef STAGEB
#undef WRITEA
#undef LOADA

    // epilogue: partial over this block's 128 cols; D frag: col=l15, row=lg*4+r
    float b1v[4], w2v[4];
    #pragma unroll
    for (int fn = 0; fn < 4; fn++) {
        int j = nc0 + wn * 64 + fn * 16 + l15;
        b1v[fn] = b1[j]; w2v[fn] = W2[j];
    }
    float ps[4][4];
    #pragma unroll
    for (int fm = 0; fm < 4; fm++) {
        #pragma unroll
        for (int r = 0; r < 4; r++) {
            float s = 0.f;
            #pragma unroll
            for (int fn = 0; fn < 4; fn++)
                s += tanhf(acc[fm][fn][r] + b1v[fn]) * w2v[fn];
            s += __shfl_xor(s, 1); s += __shfl_xor(s, 2);
            s += __shfl_xor(s, 4); s += __shfl_xor(s, 8);
            ps[fm][r] = s;
        }
    }
    __syncthreads();                       // all ds_reads of sA done -> safe to alias
    float* sRed = (float*)sA;              // [2 n-panels][128 rows], 1KB of the 16KB
    #pragma unroll
    for (int fm = 0; fm < 4; fm++)
        #pragma unroll
        for (int r = 0; r < 4; r++)
            if (l15 == 0) sRed[wn * 128 + wm * 64 + fm * 16 + lg * 4 + r] = ps[fm][r];
    __syncthreads();
    if (tid < 128)
        epart[(long)nt * (B_ * T_) + row0 + tid] = sRed[tid] + sRed[128 + tid];
}

// ---------- phase 2: rank threshold; BUILD=1 fuses epart0+epart1+b2 -> e, band list;
//                    BUILD=0 -> survivor list ----------
template<int BUILD>
__global__ __launch_bounds__(256) void k_thresh(const float* __restrict__ ep,
                                                const float* __restrict__ b2,
                                                float* __restrict__ e,
                                                int* __restrict__ counts,
                                                int* __restrict__ list,
                                                int* __restrict__ sidx,
                                                float* __restrict__ sval,
                                                int* __restrict__ scount) {
    __shared__ int   sbi[4];
    __shared__ float sbf[4];
    __shared__ int   wsum[4];
    __shared__ int   scnt;
    const int b = blockIdx.x, tid = threadIdx.x;
    const int lane = tid & 63, wid = tid >> 6;
    const int t0 = tid * 16;

    float fe[16]; unsigned ue[16];
    if (BUILD) {
        const float b2v = b2[0];
        const float* e0 = ep + (long)b * T_;
        const float* e1 = ep + (long)(B_ * T_) + (long)b * T_;
        #pragma unroll
        for (int i = 0; i < 16; i += 4) {
            float4 v0 = *(const float4*)(e0 + t0 + i);
            float4 v1 = *(const float4*)(e1 + t0 + i);
            fe[i]   = v0.x + v1.x + b2v;
            fe[i+1] = v0.y + v1.y + b2v;
            fe[i+2] = v0.z + v1.z + b2v;
            fe[i+3] = v0.w + v1.w + b2v;
        }
        #pragma unroll
        for (int i = 0; i < 16; i += 4)
            *(float4*)(e + (long)b * T_ + t0 + i) = make_float4(fe[i], fe[i+1], fe[i+2], fe[i+3]);
    } else {
        const float* eb = e + (long)b * T_;
        #pragma unroll
        for (int i = 0; i < 16; i += 4) {
            float4 v = *(const float4*)(eb + t0 + i);
            fe[i] = v.x; fe[i+1] = v.y; fe[i+2] = v.z; fe[i+3] = v.w;
        }
    }
    #pragma unroll
    for (int i = 0; i < 16; i++) ue[i] = f2s(fe[i]);

    unsigned lo = 0u, hi = 0xFFFFFFFFu;
    while (lo < hi) {
        unsigned mid = lo + ((hi - lo) >> 1);
        int c = 0;
        #pragma unroll
        for (int i = 0; i < 16; i++) c += (ue[i] <= mid) ? 1 : 0;
        int total = block_sum_i(c, sbi, tid);
        if (total >= KTH + 1) hi = mid; else lo = mid + 1;
    }
    const float thr = s2f(lo);

    if (BUILD) {
        if (tid == 0) scnt = 0;
        __syncthreads();
        #pragma unroll
        for (int i = 0; i < 16; i++) {
            if (fabsf(fe[i] - thr) <= EPSB) {
                int p = atomicAdd(&scnt, 1);
                if (p < MAXBAND) list[b * MAXBAND + p] = t0 + i;
            }
        }
        __syncthreads();
        if (tid == 0) counts[b] = scnt < MAXBAND ? scnt : MAXBAND;
    } else {
        float m = -INFINITY;
        #pragma unroll
        for (int i = 0; i < 16; i++) if (fe[i] < thr) m = fmaxf(m, fe[i]);
        m = block_max_f(m, sbf, tid);
        float s = 0.f;
        #pragma unroll
        for (int i = 0; i < 16; i++) if (fe[i] < thr) s += expf(fe[i] - m);
        s = block_sum_f(s, sbf, tid);
        const float inv = 1.0f / s;

        // deterministic t-ordered compaction: block exclusive scan of counts
        int c = 0;
        #pragma unroll
        for (int i = 0; i < 16; i++) c += (fe[i] < thr) ? 1 : 0;
        int p = c;
        #pragma unroll
        for (int o = 1; o < 64; o <<= 1) {
            int y = __shfl_up(p, o);
            if (lane >= o) p += y;
        }
        if (lane == 63) wsum[wid] = p;          // wave total
        __syncthreads();
        int base = 0;
        #pragma unroll
        for (int w = 0; w < 4; w++) base += (w < wid) ? wsum[w] : 0;
        int pos = base + p - c;                 // exclusive prefix
        #pragma unroll
        for (int i = 0; i < 16; i++) {
            if (fe[i] < thr) {
                sidx[(long)b * T_ + pos] = t0 + i;
                sval[(long)b * T_ + pos] = expf(fe[i] - m) * inv;
                pos++;
            }
        }
        if (tid == 0) scount[b] = wsum[0] + wsum[1] + wsum[2] + wsum[3];
    }
}

// ---------- phase 2.5: exact fp32 recompute of band rows, RB rows share one W1 stream ----------
__global__ __launch_bounds__(256) void k_refine(const float* __restrict__ x,
        const float* __restrict__ W1, const float* __restrict__ b1,
        const float* __restrict__ W2, const float* __restrict__ b2,
        const int* __restrict__ counts, const int* __restrict__ list,
        float* __restrict__ e) {
    const int b   = blockIdx.y;
    const int blk = blockIdx.x;            // 0..15
    const int cnt = counts[b];
    const int tid = threadIdx.x;
    __shared__ float xs[RB][D_];           // 16 KB
    __shared__ float sbf[4];

    for (int g = blk * RB; g < cnt; g += 16 * RB) {
        const int nr = min(RB, cnt - g);
        for (int j = 0; j < nr; j++) {
            const int t = list[b * MAXBAND + g + j];
            *(float4*)&xs[j][tid * 4] =
                *(const float4*)&x[((long)b * T_ + t) * D_ + tid * 4];
        }
        __syncthreads();

        float a0 = 0.f, a1 = 0.f, a2 = 0.f, a3 = 0.f;
        for (int k0 = 0; k0 < D_; k0 += 4) {
            const float w0 = W1[(long)(k0 + 0) * H_ + tid];
            const float w1v = W1[(long)(k0 + 1) * H_ + tid];
            const float w2q = W1[(long)(k0 + 2) * H_ + tid];
            const float w3 = W1[(long)(k0 + 3) * H_ + tid];
            {
                float4 xv = *(const float4*)&xs[0][k0];
                a0 = fmaf(xv.x, w0, a0); a0 = fmaf(xv.y, w1v, a0);
                a0 = fmaf(xv.z, w2q, a0); a0 = fmaf(xv.w, w3, a0);
            }
            {
                float4 xv = *(const float4*)&xs[1][k0];
                a1 = fmaf(xv.x, w0, a1); a1 = fmaf(xv.y, w1v, a1);
                a1 = fmaf(xv.z, w2q, a1); a1 = fmaf(xv.w, w3, a1);
            }
            {
                float4 xv = *(const float4*)&xs[2][k0];
                a2 = fmaf(xv.x, w0, a2); a2 = fmaf(xv.y, w1v, a2);
                a2 = fmaf(xv.z, w2q, a2); a2 = fmaf(xv.w, w3, a2);
            }
            {
                float4 xv = *(const float4*)&xs[3][k0];
                a3 = fmaf(xv.x, w0, a3); a3 = fmaf(xv.y, w1v, a3);
                a3 = fmaf(xv.z, w2q, a3); a3 = fmaf(xv.w, w3, a3);
            }
        }

        float aj[RB] = {a0, a1, a2, a3};
        for (int j = 0; j < nr; j++) {
            float v = tanhf(aj[j] + b1[tid]) * W2[tid];
            float tot = block_sum_f(v, sbf, tid);
            if (tid == 0) {
                const int t = list[b * MAXBAND + g + j];
                e[(long)b * T_ + t] = tot + b2[0];
            }
            __syncthreads();
        }
        __syncthreads();
    }
}

// ---------- phase 3: dense survivor-list PV ----------
__global__ __launch_bounds__(256) void k_pv(const float* __restrict__ x,
                                            const int* __restrict__ sidx,
                                            const float* __restrict__ sval,
                                            const int* __restrict__ scount,
                                            float* __restrict__ partial) {
    const int c = blockIdx.x, b = blockIdx.y, tid = threadIdx.x;
    const int cnt = scount[b];
    const int len = (cnt + SC - 1) / SC;       // <= 32 (cnt <= 2048)
    const int k0 = c * len;
    const int nl = min(len, cnt - k0);
    __shared__ int   si[32];
    __shared__ float sv[32];
    if (tid < nl) {
        si[tid] = sidx[(long)b * T_ + k0 + tid];
        sv[tid] = sval[(long)b * T_ + k0 + tid];
    }
    __syncthreads();

    float4 acc = {0.f, 0.f, 0.f, 0.f};
    const float* xb = x + (long)b * T_ * D_ + tid * 4;
    #pragma unroll 4
    for (int k = 0; k < nl; k++) {
        const float w = sv[k];
        float4 v = *(const float4*)(xb + (long)si[k] * D_);
        acc.x = fmaf(w, v.x, acc.x);
        acc.y = fmaf(w, v.y, acc.y);
        acc.z = fmaf(w, v.z, acc.z);
        acc.w = fmaf(w, v.w, acc.w);
    }
    *(float4*)&partial[(((long)b * SC) + c) * D_ + tid * 4] = acc;
}

// ---------- phase 4 ----------
__global__ __launch_bounds__(256) void k_red(const float* __restrict__ partial,
                                             float* __restrict__ out) {
    const int b = blockIdx.x, tid = threadIdx.x;
    float4 acc = {0.f, 0.f, 0.f, 0.f};
    #pragma unroll
    for (int c = 0; c < SC; c++) {
        float4 v = *(const float4*)&partial[(((long)b * SC) + c) * D_ + tid * 4];
        acc.x += v.x; acc.y += v.y; acc.z += v.z; acc.w += v.w;
    }
    *(float4*)&out[(long)b * D_ + tid * 4] = acc;
}

extern "C" void kernel_launch(void* const* d_in, const int* in_sizes, int n_in,
                              void* d_out, int out_size, void* d_ws, size_t ws_size,
                              hipStream_t stream) {
    const float* x  = (const float*)d_in[0];
    const float* W1 = (const float*)d_in[1];
    const float* b1 = (const float*)d_in[2];
    const float* W2 = (const float*)d_in[3];
    const float* b2 = (const float*)d_in[4];
    float* out = (float*)d_out;

    char* ws = (char*)d_ws;
    float* e       = (float*)ws;  ws += (size_t)B_ * T_ * 4;
    float* epart   = (float*)ws;  ws += (size_t)2 * B_ * T_ * 4;
    int*   sidx    = (int*)ws;    ws += (size_t)B_ * T_ * 4;
    float* sval    = (float*)ws;  ws += (size_t)B_ * T_ * 4;
    float* partial = (float*)ws;  ws += (size_t)B_ * SC * D_ * 4;
    ushort* Whi    = (ushort*)ws; ws += (size_t)H_ * D_ * 2;
    int* counts    = (int*)ws;    ws += 128;
    int* scountp   = (int*)ws;    ws += 128;
    int* list      = (int*)ws;

    k_w1t<<<dim3(D_ / 32, H_ / 32), 256, 0, stream>>>(W1, Whi);
    k_e_mfma<<<dim3(2, (B_ * T_) / 128), 256, 0, stream>>>(x, Whi, b1, W2, epart);
    k_thresh<1><<<B_, 256, 0, stream>>>(epart, b2, e, counts, list, sidx, sval, scountp);
    k_refine<<<dim3(16, B_), 256, 0, stream>>>(x, W1, b1, W2, b2, counts, list, e);
    k_thresh<0><<<B_, 256, 0, stream>>>(epart, b2, e, counts, list, sidx, sval, scountp);
    k_pv<<<dim3(SC, B_), 256, 0, stream>>>(x, sidx, sval, scountp, partial);
    k_red<<<B_, 256, 0, stream>>>(partial, out);
}